// Round 13
// baseline (176.905 us; speedup 1.0000x reference)
//
#include <hip/hip_runtime.h>

// ---------------------------------------------------------------------------
// MHLP predictor — fused f16 MFMA, per-stage LDS frag staging round.
// (Resubmission — R12 died on infra: "MI355X container failed twice", same
// acquire-level signature as R6/R7 which resolved by identical resubmit.
// Barrier structure re-audited: all __syncthreads unconditional, no
// divergent-barrier hang risk. Kernel unchanged.)
// R11 post-mortem (80 us, regressed): bias-table freed only 4 VGPRs (batch
// arrays + accs set peak pressure), occupancy flat -> REVERTED; base = R10
// (74.8 us). R10 model: no pipe saturated; 16384 waves x 64 KB frag loads
// = ~13 TB/s of L2 traffic; frag set (76 KB) > L1 (32 KB) -> ~0% L1 hit ->
// every wave pays L2 latency+queueing on every frag. Fix: fetch ONCE PER
// BLOCK: one 24 KB staging buffer reused per stage (W1 -> W2 -> IP ->
// OP+W3), cooperative 256-thread fill + barrier, then B-frags come from
// conflict-free ds_read_b128 (~6cy) instead of ~250cy L2. L2 frag traffic
// /4. LDS 24K stage + 4x6.9K scratch = 52.2 KB -> 3 blocks/CU = 12
// waves/CU = exactly today's measured occupancy (nothing lost). R0's
// staging failure was whole-set persistent staging at 2 blk/CU; this is
// stage-windowed at iso-occupancy.
// Predict: k_fused 74.8 -> ~55-65 us, VALU 45->55-65%, Mfma ~15%,
// LDS_Block_Size 52224, Occ ~35-40, absmax 0.003173828 identical.
// ---------------------------------------------------------------------------

using s8v = __attribute__((ext_vector_type(8))) short;
using h8  = __attribute__((ext_vector_type(8))) _Float16;
using h2v = __attribute__((ext_vector_type(2))) _Float16;
using f4  = __attribute__((ext_vector_type(4))) float;

// d_ws u16-unit layout (pre-swizzled f16 weight frags + tables)
#define WF_W1   0        // 12288  (K=75(+bias row 75)->KS=3, NT=8)
#define WF_W2   12288    // 8192   (K=128->KS=4, NT=4)
#define WF_IP   20480    // 12288  (K=64->KS=2, NT=12)
#define WF_OP   32768    // 4096   (K=64->KS=2, NT=4)  [OP+W3 contiguous]
#define WF_W3   36864    // 2048   (K=64->KS=2, NT=2)
#define WF_HWE  38912    // 256    (hw_embed f16 [4][64])
#define TQ0     39168    // 256    (q0+bq per hw, f16 [4][64])
#define TK0     39424    // 256    (raw k0)
#define TV0B    39680    // 256    (v0+bv)
#define TV0R    39936    // 256    (raw v0)
#define TBQ     40192    // 64     (q bias f16)

// LDS map (u16): frag staging @0 (12288 max), per-wave scratch after.
#define SCR     12288
#define PWS     3456     // u16; 6912 B per wave
// total = 12288 + 4*3456 = 26112 u16 = 52224 B -> 3 blocks/CU

__device__ __forceinline__ unsigned short f2h(float f) {
  _Float16 h = (_Float16)f;
  return __builtin_bit_cast(unsigned short, h);
}

__device__ __forceinline__ float dot8(h8 a, h8 b, float acc) {
  const f4 af = __builtin_bit_cast(f4, a), bf = __builtin_bit_cast(f4, b);
#pragma unroll
  for (int u = 0; u < 4; ++u)
    acc = __builtin_amdgcn_fdot2(__builtin_bit_cast(h2v, af[u]),
                                 __builtin_bit_cast(h2v, bf[u]), acc, false);
  return acc;
}

// cooperative global->LDS copy of nf4 f4-words (256 threads)
__device__ __forceinline__ void stage(const unsigned short* __restrict__ src,
                                      unsigned short* __restrict__ dst,
                                      int nf4, int tid) {
  const f4* s = (const f4*)src;
  f4* d = (f4*)dst;
  for (int i = tid; i < nf4; i += 256) d[i] = s[i];
}

// swizzle W[N][Kreal] row-major f32 -> B-frag f16 layout; optional bias row
// at k == Kreal (folded-bias trick).
__device__ __forceinline__ void swz(const float* __restrict__ W,
                                    const float* __restrict__ bias,
                                    unsigned short* __restrict__ dst,
                                    int Kreal, int KS, int NT, int t, int stride) {
  const int total = KS * NT * 512;
  for (int i = t; i < total; i += stride) {
    const int j = i & 7, ln = (i >> 3) & 63, fr = i >> 9;
    const int nt = fr % NT, ks = fr / NT;
    const int n = nt * 16 + (ln & 15);
    const int k = ks * 32 + (ln >> 4) * 8 + j;
    float v = 0.f;
    if (k < Kreal) v = W[n * Kreal + k];
    else if (bias && k == Kreal) v = bias[n];
    dst[i] = f2h(v);
  }
}

__global__ void k_pre(const float* __restrict__ hwe,
                      const float* __restrict__ W1, const float* __restrict__ b1,
                      const float* __restrict__ W2,
                      const float* __restrict__ ipw, const float* __restrict__ ipb,
                      const float* __restrict__ opw,
                      const float* __restrict__ W3,
                      unsigned short* __restrict__ ws) {
  const int t = blockIdx.x * 256 + threadIdx.x;
  const int stride = gridDim.x * 256;
  swz(W1,  b1,      ws + WF_W1, 75, 3, 8, t, stride);
  swz(W2,  nullptr, ws + WF_W2, 128, 4, 4, t, stride);
  swz(ipw, nullptr, ws + WF_IP, 64, 2, 12, t, stride);
  swz(opw, nullptr, ws + WF_OP, 64, 2, 4, t, stride);
  swz(W3,  nullptr, ws + WF_W3, 64, 2, 2, t, stride);
  for (int i = t; i < 256; i += stride) ws[WF_HWE + i] = f2h(hwe[i]);
  // token-0 qkv tables: qkv0[hw][n] = hw_emb[hw] . in_proj_w[n] (+ bias var.)
  for (int i = t; i < 768; i += stride) {
    const int hw = i / 192, n = i - hw * 192;
    const float* er = hwe + hw * 64;
    const float* wr = ipw + (size_t)n * 64;
    float acc = 0.f;
#pragma unroll 8
    for (int d = 0; d < 64; ++d) acc += er[d] * wr[d];
    if (n < 64)       ws[TQ0  + hw * 64 + n]         = f2h(acc + ipb[n]);
    else if (n < 128) ws[TK0  + hw * 64 + (n - 64)]  = f2h(acc);
    else {            ws[TV0B + hw * 64 + (n - 128)] = f2h(acc + ipb[n]);
                      ws[TV0R + hw * 64 + (n - 128)] = f2h(acc); }
  }
  for (int i = t; i < 64; i += stride) ws[TBQ + i] = f2h(ipb[i]);
}

// ======================= fused: encoder + attention + head =================
__global__ __launch_bounds__(256, 4) void k_fused(
    const int* __restrict__ g_hw,
    const int* __restrict__ g_op, const int* __restrict__ g_wd,
    const float* __restrict__ g_hwe,
    const float* __restrict__ g_b2,
    const float* __restrict__ g_ln1g, const float* __restrict__ g_ln1b,
    const float* __restrict__ g_opb,
    const float* __restrict__ g_ln2g, const float* __restrict__ g_ln2b,
    const float* __restrict__ g_b3,  const float* __restrict__ g_W4,
    const float* __restrict__ g_b4,
    const unsigned short* __restrict__ wsf,   // d_ws base (u16)
    float* __restrict__ g_out) {
  __shared__ __align__(16) unsigned short sm[SCR + 4 * PWS];
  const int tid = threadIdx.x;
  const int wave = tid >> 6, lane = tid & 63;
  const int quad = lane >> 4, l15 = lane & 15;
  unsigned short* pw = sm + SCR + wave * PWS;
  const int m0 = (blockIdx.x * 4 + wave) * 16;   // 4096 blocks x 4 waves

  // ---- stage W1 frags (1536 f4) while index/bias loads are in flight ----
  stage(wsf + WF_W1, sm, 1536, tid);

  // ---- index loads (lanes 0..15) + in-wave broadcasts ----
  int hwv = 0, c0 = 0, c1 = 0, c2 = 0, c3 = 0, c4 = 0;
  if (lane < 16) {
    const int smp = m0 + lane;
    hwv = g_hw[smp];
    c0 =      g_op[smp * 5 + 0] * 3 + g_wd[smp * 5 + 0];
    c1 = 15 + g_op[smp * 5 + 1] * 3 + g_wd[smp * 5 + 1];
    c2 = 30 + g_op[smp * 5 + 2] * 3 + g_wd[smp * 5 + 2];
    c3 = 45 + g_op[smp * 5 + 3] * 3 + g_wd[smp * 5 + 3];
    c4 = 60 + g_op[smp * 5 + 4] * 3 + g_wd[smp * 5 + 4];
  }
  const int t0 = __shfl(c0, l15), t1 = __shfl(c1, l15), t2 = __shfl(c2, l15);
  const int t3 = __shfl(c3, l15), t4 = __shfl(c4, l15);
  const int hwrow = __shfl(hwv, l15);

  // ---- hoisted bias/param loads ----
  float b2v[4], l1gv[4], l1bv[4], opbv[4], l2gv[4], l2bv[4];
#pragma unroll
  for (int nt = 0; nt < 4; ++nt) {
    const int col = nt * 16 + l15;
    b2v[nt] = g_b2[col];  l1gv[nt] = g_ln1g[col]; l1bv[nt] = g_ln1b[col];
    opbv[nt] = g_opb[col]; l2gv[nt] = g_ln2g[col]; l2bv[nt] = g_ln2b[col];
  }
  float b3v[2], w4vv[2];
#pragma unroll
  for (int nt = 0; nt < 2; ++nt) {
    b3v[nt] = g_b3[nt * 16 + l15];
    w4vv[nt] = g_W4[nt * 16 + l15];
  }
  const float b4v = g_b4[0];

  // ---- one-hot via 96-bit membership mask ----
  unsigned w0 = (1u << t0) | (1u << t1);
  unsigned w1 = 1u << (t3 - 32);
  unsigned w2 = 1u << 11;
  {
    const unsigned m2 = 1u << (t2 & 31);
    w0 |= (t2 < 32) ? m2 : 0u;
    w1 |= (t2 >= 32) ? m2 : 0u;
    const unsigned m4 = 1u << (t4 & 31);
    w1 |= (t4 < 64) ? m4 : 0u;
    w2 |= (t4 >= 64) ? m4 : 0u;
  }
  h8 aoh[3];
#pragma unroll
  for (int ks = 0; ks < 3; ++ks) {
    const unsigned wm = (ks == 0) ? w0 : (ks == 1) ? w1 : w2;
    const unsigned sh = wm >> (quad * 8);
    s8v a;
#pragma unroll
    for (int j = 0; j < 8; ++j)
      a[j] = ((sh >> j) & 1u) ? (short)0x3C00 : (short)0;
    aoh[ks] = __builtin_bit_cast(h8, a);
  }

  __syncthreads();   // W1 frags staged

  // S1: h = relu(onehot @ [W1;b1]^T) -> pw[0..2176) stride 136 (f16)
#pragma unroll
  for (int half = 0; half < 2; ++half) {
    h8 bf[12];
#pragma unroll
    for (int n2 = 0; n2 < 4; ++n2)
#pragma unroll
      for (int ks = 0; ks < 3; ++ks)
        bf[n2 * 3 + ks] = *(const h8*)(sm +
            ((ks * 8 + half * 4 + n2) * 64 + lane) * 8);
#pragma unroll
    for (int n2 = 0; n2 < 4; ++n2) {
      f4 acc = {0.f, 0.f, 0.f, 0.f};
#pragma unroll
      for (int ks = 0; ks < 3; ++ks)
        acc = __builtin_amdgcn_mfma_f32_16x16x32_f16(aoh[ks], bf[n2 * 3 + ks],
                                                     acc, 0, 0, 0);
      const int col = (half * 4 + n2) * 16 + l15;
#pragma unroll
      for (int r = 0; r < 4; ++r) {
        float v = acc[r];
        v = v > 0.f ? v : 0.f;
        pw[(quad * 4 + r) * 136 + col] = f2h(v);
      }
    }
  }

  __syncthreads();                    // all waves done reading W1
  stage(wsf + WF_W2, sm, 1024, tid);  // W2 frags (1024 f4)

  // a2 frags from scratch (not staging region) — safe before barrier
  h8 a2[4];
#pragma unroll
  for (int ks = 0; ks < 4; ++ks)
    a2[ks] = *(const h8*)(pw + l15 * 136 + ks * 32 + quad * 8);

  __syncthreads();   // W2 staged

  // S2: arch = LN1(h @ W2^T + b2); arch f16 -> pw@0 stride 72,
  // residual f32 in regs.  Batched: 2 halves x 8 frags.
  float archres[4][4];   // LN1 out f32, layout (row=quad*4+r, col=nt*16+l15)
  {
    float val[4][4];
#pragma unroll
    for (int half = 0; half < 2; ++half) {
      h8 bf[8];
#pragma unroll
      for (int n2 = 0; n2 < 2; ++n2)
#pragma unroll
        for (int ks = 0; ks < 4; ++ks)
          bf[n2 * 4 + ks] = *(const h8*)(sm +
              ((ks * 4 + half * 2 + n2) * 64 + lane) * 8);
#pragma unroll
      for (int n2 = 0; n2 < 2; ++n2) {
        f4 acc = {0.f, 0.f, 0.f, 0.f};
#pragma unroll
        for (int ks = 0; ks < 4; ++ks)
          acc = __builtin_amdgcn_mfma_f32_16x16x32_f16(a2[ks], bf[n2 * 4 + ks],
                                                       acc, 0, 0, 0);
        const int nt = half * 2 + n2;
#pragma unroll
        for (int r = 0; r < 4; ++r) val[nt][r] = acc[r] + b2v[nt];
      }
    }
#pragma unroll
    for (int r = 0; r < 4; ++r) {
      float s = val[0][r] + val[1][r] + val[2][r] + val[3][r];
      float q = val[0][r] * val[0][r] + val[1][r] * val[1][r] +
                val[2][r] * val[2][r] + val[3][r] * val[3][r];
#pragma unroll
      for (int off = 1; off <= 8; off <<= 1) {
        s += __shfl_xor(s, off);
        q += __shfl_xor(q, off);
      }
      const float mean = s * (1.f / 64.f);
      const float var  = q * (1.f / 64.f) - mean * mean;
      const float rstd = rsqrtf(var + 1e-5f);
#pragma unroll
      for (int nt = 0; nt < 4; ++nt) {
        const int col = nt * 16 + l15;
        const float xn = (val[nt][r] - mean) * rstd * l1gv[nt] + l1bv[nt];
        archres[nt][r] = xn;
        pw[(quad * 4 + r) * 72 + col] = f2h(xn);
      }
    }
  }

  __syncthreads();                    // all waves done reading W2
  stage(wsf + WF_IP, sm, 1536, tid);  // IP frags (1536 f4)

  h8 at1[2];
#pragma unroll
  for (int ks = 0; ks < 2; ++ks)
    at1[ks] = *(const h8*)(pw + l15 * 72 + ks * 32 + quad * 8);

  __syncthreads();   // IP staged

  // S3 producer: arch-token q1/k1/v1 (no biases) -> LDS f16
  //   Q1 [16][72] @0 (over arch; at1 already in regs), K1 @1152, V1 @2304
#pragma unroll
  for (int hh = 0; hh < 2; ++hh) {
    h8 bf[12];   // [h2][qkv][ks]
#pragma unroll
    for (int h2 = 0; h2 < 2; ++h2) {
      const int h = hh * 2 + h2;
#pragma unroll
      for (int ks = 0; ks < 2; ++ks) {
        bf[h2 * 6 + 0 + ks] = *(const h8*)(sm + ((ks * 12 + h    ) * 64 + lane) * 8);
        bf[h2 * 6 + 2 + ks] = *(const h8*)(sm + ((ks * 12 + h + 4) * 64 + lane) * 8);
        bf[h2 * 6 + 4 + ks] = *(const h8*)(sm + ((ks * 12 + h + 8) * 64 + lane) * 8);
      }
    }
#pragma unroll
    for (int h2 = 0; h2 < 2; ++h2) {
      const int h = hh * 2 + h2;
      f4 aq = {0.f,0.f,0.f,0.f}, ak = {0.f,0.f,0.f,0.f}, av = {0.f,0.f,0.f,0.f};
#pragma unroll
      for (int ks = 0; ks < 2; ++ks) {
        aq = __builtin_amdgcn_mfma_f32_16x16x32_f16(at1[ks], bf[h2 * 6 + 0 + ks], aq, 0, 0, 0);
        ak = __builtin_amdgcn_mfma_f32_16x16x32_f16(at1[ks], bf[h2 * 6 + 2 + ks], ak, 0, 0, 0);
        av = __builtin_amdgcn_mfma_f32_16x16x32_f16(at1[ks], bf[h2 * 6 + 4 + ks], av, 0, 0, 0);
      }
      const int col = h * 16 + l15;
#pragma unroll
      for (int r = 0; r < 4; ++r) {
        const int row = quad * 4 + r;
        pw[row * 72 + col]        = f2h(aq[r]);
        pw[1152 + row * 72 + col] = f2h(ak[r]);
        pw[2304 + row * 72 + col] = f2h(av[r]);
      }
    }
  }

  // S4 consumer: lane = (sample s=l15, head=quad); in-thread fdot2 scores.
  {
    const int qb = quad * 16;
    const unsigned short* q1p = pw + l15 * 72 + qb;
    const h8 q1a = *(const h8*)(q1p),          q1b = *(const h8*)(q1p + 8);
    const h8 k1a = *(const h8*)(q1p + 1152),   k1b = *(const h8*)(q1p + 1160);
    const h8 v1a = *(const h8*)(q1p + 2304),   v1b = *(const h8*)(q1p + 2312);
    const int tb = hwrow * 64 + qb;
    const h8 Q0a = *(const h8*)(wsf + TQ0 + tb),  Q0b = *(const h8*)(wsf + TQ0 + tb + 8);
    const h8 K0a = *(const h8*)(wsf + TK0 + tb),  K0b = *(const h8*)(wsf + TK0 + tb + 8);
    const h8 VBa = *(const h8*)(wsf + TV0B + tb), VBb = *(const h8*)(wsf + TV0B + tb + 8);
    const h8 VRa = *(const h8*)(wsf + TV0R + tb), VRb = *(const h8*)(wsf + TV0R + tb + 8);
    const h8 bqa = *(const h8*)(wsf + TBQ + qb),  bqb = *(const h8*)(wsf + TBQ + qb + 8);
    const h8 dka = k1a - K0a, dkb = k1b - K0b;   // bk cancels
    const float d0 = dot8(Q0a, dka, dot8(Q0b, dkb, 0.f));
    const float d1 = dot8(q1a, dka, dot8(q1b, dkb,
                     dot8(bqa, dka, dot8(bqb, dkb, 0.f))));
    const float a01 = 1.f / (1.f + __expf(-d0 * 0.25f));
    const float a11 = 1.f / (1.f + __expf(-d1 * 0.25f));
    const h8 dva = v1a - VRa, dvb = v1b - VRb;   // bv cancels in dv
    h8 c0a, c0b, c1a, c1b;                       // ctx math in f32
#pragma unroll
    for (int j = 0; j < 8; ++j) {
      const float vb0 = (float)VBa[j], dv0 = (float)dva[j];
      const float vb1 = (float)VBb[j], dv1 = (float)dvb[j];
      c0a[j] = (_Float16)(vb0 + a01 * dv0);
      c0b[j] = (_Float16)(vb1 + a01 * dv1);
      c1a[j] = (_Float16)(vb0 + a11 * dv0);
      c1b[j] = (_Float16)(vb1 + a11 * dv1);
    }
    *(h8*)(pw + l15 * 72 + qb)            = c0a;
    *(h8*)(pw + l15 * 72 + qb + 8)        = c0b;
    *(h8*)(pw + (16 + l15) * 72 + qb)     = c1a;
    *(h8*)(pw + (16 + l15) * 72 + qb + 8) = c1b;
  }

  __syncthreads();                    // all waves done reading IP
  stage(wsf + WF_OP, sm, 768, tid);   // OP (512 f4) + W3 (256 f4) contiguous

  // ca frags from scratch — safe before barrier
  h8 ca[2][2];
#pragma unroll
  for (int mt = 0; mt < 2; ++mt)
#pragma unroll
    for (int ks = 0; ks < 2; ++ks)
      ca[mt][ks] = *(const h8*)(pw + (mt * 16 + l15) * 72 + ks * 32 + quad * 8);

  __syncthreads();   // OP+W3 staged

  // S5: out_proj + residual + LN2 + mean-pool -> pool f16 @0
  f4 oacc[2][4];
  {
    h8 bf[8];
#pragma unroll
    for (int nt = 0; nt < 4; ++nt)
#pragma unroll
      for (int ks = 0; ks < 2; ++ks)
        bf[nt * 2 + ks] = *(const h8*)(sm + ((ks * 4 + nt) * 64 + lane) * 8);
#pragma unroll
    for (int nt = 0; nt < 4; ++nt)
#pragma unroll
      for (int mt = 0; mt < 2; ++mt) {
        f4 acc = {0.f, 0.f, 0.f, 0.f};
        acc = __builtin_amdgcn_mfma_f32_16x16x32_f16(ca[mt][0], bf[nt * 2 + 0], acc, 0, 0, 0);
        acc = __builtin_amdgcn_mfma_f32_16x16x32_f16(ca[mt][1], bf[nt * 2 + 1], acc, 0, 0, 0);
        oacc[mt][nt] = acc;
      }
  }
  float pool[4][4];
#pragma unroll
  for (int mt = 0; mt < 2; ++mt) {
    float val[4][4];
#pragma unroll
    for (int r = 0; r < 4; ++r) {
      if (mt == 0) {
        const int hr = __shfl(hwv, quad * 4 + r);
#pragma unroll
        for (int nt = 0; nt < 4; ++nt)
          val[nt][r] = oacc[0][nt][r] + opbv[nt] + g_hwe[hr * 64 + nt * 16 + l15];
      } else {
#pragma unroll
        for (int nt = 0; nt < 4; ++nt)
          val[nt][r] = oacc[1][nt][r] + opbv[nt] + archres[nt][r];
      }
    }
#pragma unroll
    for (int r = 0; r < 4; ++r) {
      float s = val[0][r] + val[1][r] + val[2][r] + val[3][r];
      float q = val[0][r] * val[0][r] + val[1][r] * val[1][r] +
                val[2][r] * val[2][r] + val[3][r] * val[3][r];
#pragma unroll
      for (int off = 1; off <= 8; off <<= 1) {
        s += __shfl_xor(s, off);
        q += __shfl_xor(q, off);
      }
      const float mean = s * (1.f / 64.f);
      const float var  = q * (1.f / 64.f) - mean * mean;
      const float rstd = rsqrtf(var + 1e-5f);
#pragma unroll
      for (int nt = 0; nt < 4; ++nt) {
        const float xn = (val[nt][r] - mean) * rstd * l2gv[nt] + l2bv[nt];
        if (mt == 0) pool[nt][r] = 0.5f * xn;
        else         pool[nt][r] += 0.5f * xn;
      }
    }
  }
#pragma unroll
  for (int nt = 0; nt < 4; ++nt)
#pragma unroll
    for (int r = 0; r < 4; ++r)
      pw[(quad * 4 + r) * 72 + nt * 16 + l15] = f2h(pool[nt][r]);

  // S6: head (W3 staged at sm+4096)
  h8 pa[2];
#pragma unroll
  for (int ks = 0; ks < 2; ++ks)
    pa[ks] = *(const h8*)(pw + l15 * 72 + ks * 32 + quad * 8);
  float part[4] = {0.f, 0.f, 0.f, 0.f};
  {
    h8 bf[4];
#pragma unroll
    for (int nt = 0; nt < 2; ++nt)
#pragma unroll
      for (int ks = 0; ks < 2; ++ks)
        bf[nt * 2 + ks] = *(const h8*)(sm + 4096 + ((ks * 2 + nt) * 64 + lane) * 8);
#pragma unroll
    for (int nt = 0; nt < 2; ++nt) {
      f4 acc = {0.f, 0.f, 0.f, 0.f};
      acc = __builtin_amdgcn_mfma_f32_16x16x32_f16(pa[0], bf[nt * 2 + 0], acc, 0, 0, 0);
      acc = __builtin_amdgcn_mfma_f32_16x16x32_f16(pa[1], bf[nt * 2 + 1], acc, 0, 0, 0);
#pragma unroll
      for (int r = 0; r < 4; ++r) {
        float y = acc[r] + b3v[nt];
        y = y > 0.f ? y : 0.f;
        part[r] += y * w4vv[nt];
      }
    }
  }
#pragma unroll
  for (int off = 1; off <= 8; off <<= 1)
#pragma unroll
    for (int r = 0; r < 4; ++r)
      part[r] += __shfl_xor(part[r], off);
  if (l15 == 0) {
#pragma unroll
    for (int r = 0; r < 4; ++r)
      g_out[m0 + quad * 4 + r] = part[r] + b4v;
  }
}

extern "C" void kernel_launch(void* const* d_in, const int* in_sizes, int n_in,
                              void* d_out, int out_size, void* d_ws, size_t ws_size,
                              hipStream_t stream) {
  (void)in_sizes; (void)n_in; (void)out_size; (void)ws_size;
  unsigned short* ws = (unsigned short*)d_ws;

  k_pre<<<64, 256, 0, stream>>>(
      (const float*)d_in[3], (const float*)d_in[4], (const float*)d_in[5],
      (const float*)d_in[6], (const float*)d_in[10], (const float*)d_in[11],
      (const float*)d_in[12], (const float*)d_in[16], ws);

  k_fused<<<4096, 256, 0, stream>>>(
      (const int*)d_in[0],
      (const int*)d_in[1], (const int*)d_in[2],
      (const float*)d_in[3],
      (const float*)d_in[7],
      (const float*)d_in[8], (const float*)d_in[9],
      (const float*)d_in[13],
      (const float*)d_in[14], (const float*)d_in[15],
      (const float*)d_in[17], (const float*)d_in[18],
      (const float*)d_in[19],
      ws, (float*)d_out);
}

// Round 14
// 163.632 us; speedup vs baseline: 1.0811x; 1.0811x over previous
//
#include <hip/hip_runtime.h>

// ---------------------------------------------------------------------------
// MHLP predictor — fused f16 MFMA, two-tile-per-wave round.
// R13 post-mortem (87.3 us, REGRESSED; reverted): staging removed L2 frag
// traffic but FETCH unchanged + occupancy 37->29 + 8 lockstep barriers ->
// falsifies "L2 queueing" model. R10's +15% came from MLP vs LATENCY;
// barriers destroy overlap. Base = R10 (74.8).
// This round: amortize frag loads 2x WITHOUT barriers — each wave processes
// TWO 16-sample tiles (32 samples). bf[] batches load once, feed MFMAs for
// both tiles; two independent dep chains interleave in-wave (ILP ~= 2x
// occupancy at same reg sets); biases/indices shared. Waves halve (8192).
// 128-thr 2-wave blocks, 2x3456 u16 scratch/wave -> 27648 B/block ->
// 5 blocks/CU = 10 waves/CU (320 samples in flight vs R10's 192, +67%).
// Loose __launch_bounds__(128,2) (budget 256; no forced spill — R5 lesson).
// S5/S6 finish tile A before B with bf live to cap pressure.
// Predict: VGPR ~110-140 (WRITE_SIZE ~1 MB = no-spill tripwire), Occ
// ~25-31%, k_fused 74.8 -> ~58-68 us, Mfma ~16-19%, VALU ~55-65%,
// absmax 0.003173828 identical.
// ---------------------------------------------------------------------------

using s8v = __attribute__((ext_vector_type(8))) short;
using h8  = __attribute__((ext_vector_type(8))) _Float16;
using h2v = __attribute__((ext_vector_type(2))) _Float16;
using f4  = __attribute__((ext_vector_type(4))) float;

// d_ws u16-unit layout (pre-swizzled f16 weight frags + tables)
#define WF_W1   0        // 12288  (K=75(+bias row 75)->KS=3, NT=8)
#define WF_W2   12288    // 8192   (K=128->KS=4, NT=4)
#define WF_IP   20480    // 12288  (K=64->KS=2, NT=12)
#define WF_OP   32768    // 4096   (K=64->KS=2, NT=4)
#define WF_W3   36864    // 2048   (K=64->KS=2, NT=2)
#define WF_HWE  38912    // 256    (hw_embed f16 [4][64])
#define TQ0     39168    // 256    (q0+bq per hw, f16 [4][64])
#define TK0     39424    // 256    (raw k0)
#define TV0B    39680    // 256    (v0+bv)
#define TV0R    39936    // 256    (raw v0)
#define TBQ     40192    // 64     (q bias f16)

// per-TILE LDS scratch (u16); per wave = 2 tiles
#define PWS     3456     // u16 per tile
#define WPS     6912     // u16 per wave (2 tiles)

__device__ __forceinline__ unsigned short f2h(float f) {
  _Float16 h = (_Float16)f;
  return __builtin_bit_cast(unsigned short, h);
}

__device__ __forceinline__ float dot8(h8 a, h8 b, float acc) {
  const f4 af = __builtin_bit_cast(f4, a), bf = __builtin_bit_cast(f4, b);
#pragma unroll
  for (int u = 0; u < 4; ++u)
    acc = __builtin_amdgcn_fdot2(__builtin_bit_cast(h2v, af[u]),
                                 __builtin_bit_cast(h2v, bf[u]), acc, false);
  return acc;
}

// swizzle W[N][Kreal] row-major f32 -> B-frag f16 layout; optional bias row
// at k == Kreal (folded-bias trick).
__device__ __forceinline__ void swz(const float* __restrict__ W,
                                    const float* __restrict__ bias,
                                    unsigned short* __restrict__ dst,
                                    int Kreal, int KS, int NT, int t, int stride) {
  const int total = KS * NT * 512;
  for (int i = t; i < total; i += stride) {
    const int j = i & 7, ln = (i >> 3) & 63, fr = i >> 9;
    const int nt = fr % NT, ks = fr / NT;
    const int n = nt * 16 + (ln & 15);
    const int k = ks * 32 + (ln >> 4) * 8 + j;
    float v = 0.f;
    if (k < Kreal) v = W[n * Kreal + k];
    else if (bias && k == Kreal) v = bias[n];
    dst[i] = f2h(v);
  }
}

__global__ void k_pre(const float* __restrict__ hwe,
                      const float* __restrict__ W1, const float* __restrict__ b1,
                      const float* __restrict__ W2,
                      const float* __restrict__ ipw, const float* __restrict__ ipb,
                      const float* __restrict__ opw,
                      const float* __restrict__ W3,
                      unsigned short* __restrict__ ws) {
  const int t = blockIdx.x * 256 + threadIdx.x;
  const int stride = gridDim.x * 256;
  swz(W1,  b1,      ws + WF_W1, 75, 3, 8, t, stride);
  swz(W2,  nullptr, ws + WF_W2, 128, 4, 4, t, stride);
  swz(ipw, nullptr, ws + WF_IP, 64, 2, 12, t, stride);
  swz(opw, nullptr, ws + WF_OP, 64, 2, 4, t, stride);
  swz(W3,  nullptr, ws + WF_W3, 64, 2, 2, t, stride);
  for (int i = t; i < 256; i += stride) ws[WF_HWE + i] = f2h(hwe[i]);
  // token-0 qkv tables: qkv0[hw][n] = hw_emb[hw] . in_proj_w[n] (+ bias var.)
  for (int i = t; i < 768; i += stride) {
    const int hw = i / 192, n = i - hw * 192;
    const float* er = hwe + hw * 64;
    const float* wr = ipw + (size_t)n * 64;
    float acc = 0.f;
#pragma unroll 8
    for (int d = 0; d < 64; ++d) acc += er[d] * wr[d];
    if (n < 64)       ws[TQ0  + hw * 64 + n]         = f2h(acc + ipb[n]);
    else if (n < 128) ws[TK0  + hw * 64 + (n - 64)]  = f2h(acc);
    else {            ws[TV0B + hw * 64 + (n - 128)] = f2h(acc + ipb[n]);
                      ws[TV0R + hw * 64 + (n - 128)] = f2h(acc); }
  }
  for (int i = t; i < 64; i += stride) ws[TBQ + i] = f2h(ipb[i]);
}

// ======================= fused: encoder + attention + head =================
__global__ __launch_bounds__(128, 2) void k_fused(
    const int* __restrict__ g_hw,
    const int* __restrict__ g_op, const int* __restrict__ g_wd,
    const float* __restrict__ g_hwe,
    const float* __restrict__ g_b2,
    const float* __restrict__ g_ln1g, const float* __restrict__ g_ln1b,
    const float* __restrict__ g_opb,
    const float* __restrict__ g_ln2g, const float* __restrict__ g_ln2b,
    const float* __restrict__ g_b3,  const float* __restrict__ g_W4,
    const float* __restrict__ g_b4,
    const unsigned short* __restrict__ wsf,   // d_ws base (u16)
    float* __restrict__ g_out) {
  __shared__ __align__(16) unsigned short sm[2 * WPS];
  const int tid = threadIdx.x;
  const int wave = tid >> 6, lane = tid & 63;
  const int quad = lane >> 4, l15 = lane & 15;
  unsigned short* pwA = sm + wave * WPS;
  unsigned short* pwB = pwA + PWS;
  const int m0 = (blockIdx.x * 2 + wave) * 32;   // 4096 blocks x 2 waves x 32

  // ---- index loads (lanes 0..31: A=0..15, B=16..31) + broadcasts ----
  int hwv = 0, c0 = 0, c1 = 0, c2 = 0, c3 = 0, c4 = 0;
  if (lane < 32) {
    const int smp = m0 + lane;
    hwv = g_hw[smp];
    c0 =      g_op[smp * 5 + 0] * 3 + g_wd[smp * 5 + 0];
    c1 = 15 + g_op[smp * 5 + 1] * 3 + g_wd[smp * 5 + 1];
    c2 = 30 + g_op[smp * 5 + 2] * 3 + g_wd[smp * 5 + 2];
    c3 = 45 + g_op[smp * 5 + 3] * 3 + g_wd[smp * 5 + 3];
    c4 = 60 + g_op[smp * 5 + 4] * 3 + g_wd[smp * 5 + 4];
  }
  const int tA0 = __shfl(c0, l15), tA1 = __shfl(c1, l15), tA2 = __shfl(c2, l15);
  const int tA3 = __shfl(c3, l15), tA4 = __shfl(c4, l15);
  const int tB0 = __shfl(c0, 16 + l15), tB1 = __shfl(c1, 16 + l15);
  const int tB2 = __shfl(c2, 16 + l15), tB3 = __shfl(c3, 16 + l15);
  const int tB4 = __shfl(c4, 16 + l15);
  const int hwrowA = __shfl(hwv, l15), hwrowB = __shfl(hwv, 16 + l15);

  // ---- hoisted bias/param loads (shared by both tiles) ----
  float b2v[4], l1gv[4], l1bv[4], opbv[4], l2gv[4], l2bv[4];
#pragma unroll
  for (int nt = 0; nt < 4; ++nt) {
    const int col = nt * 16 + l15;
    b2v[nt] = g_b2[col];  l1gv[nt] = g_ln1g[col]; l1bv[nt] = g_ln1b[col];
    opbv[nt] = g_opb[col]; l2gv[nt] = g_ln2g[col]; l2bv[nt] = g_ln2b[col];
  }
  float b3v[2], w4vv[2];
#pragma unroll
  for (int nt = 0; nt < 2; ++nt) {
    b3v[nt] = g_b3[nt * 16 + l15];
    w4vv[nt] = g_W4[nt * 16 + l15];
  }
  const float b4v = g_b4[0];

  // ---- one-hot via 96-bit membership mask, per tile ----
  h8 aohA[3], aohB[3];
  {
    unsigned wa0 = (1u << tA0) | (1u << tA1);
    unsigned wa1 = 1u << (tA3 - 32);
    unsigned wa2 = 1u << 11;
    const unsigned ma2 = 1u << (tA2 & 31);
    wa0 |= (tA2 < 32) ? ma2 : 0u;  wa1 |= (tA2 >= 32) ? ma2 : 0u;
    const unsigned ma4 = 1u << (tA4 & 31);
    wa1 |= (tA4 < 64) ? ma4 : 0u;  wa2 |= (tA4 >= 64) ? ma4 : 0u;
    unsigned wb0 = (1u << tB0) | (1u << tB1);
    unsigned wb1 = 1u << (tB3 - 32);
    unsigned wb2 = 1u << 11;
    const unsigned mb2 = 1u << (tB2 & 31);
    wb0 |= (tB2 < 32) ? mb2 : 0u;  wb1 |= (tB2 >= 32) ? mb2 : 0u;
    const unsigned mb4 = 1u << (tB4 & 31);
    wb1 |= (tB4 < 64) ? mb4 : 0u;  wb2 |= (tB4 >= 64) ? mb4 : 0u;
#pragma unroll
    for (int ks = 0; ks < 3; ++ks) {
      const unsigned wma = (ks == 0) ? wa0 : (ks == 1) ? wa1 : wa2;
      const unsigned wmb = (ks == 0) ? wb0 : (ks == 1) ? wb1 : wb2;
      const unsigned sa = wma >> (quad * 8), sb = wmb >> (quad * 8);
      s8v a, b;
#pragma unroll
      for (int j = 0; j < 8; ++j) {
        a[j] = ((sa >> j) & 1u) ? (short)0x3C00 : (short)0;
        b[j] = ((sb >> j) & 1u) ? (short)0x3C00 : (short)0;
      }
      aohA[ks] = __builtin_bit_cast(h8, a);
      aohB[ks] = __builtin_bit_cast(h8, b);
    }
  }

  // S1: h = relu(onehot @ [W1;b1]^T) -> h[16][136] in pwA/pwB
  // bf batch loaded ONCE, feeds both tiles' MFMAs.
#pragma unroll
  for (int half = 0; half < 2; ++half) {
    h8 bf[12];
#pragma unroll
    for (int n2 = 0; n2 < 4; ++n2)
#pragma unroll
      for (int ks = 0; ks < 3; ++ks)
        bf[n2 * 3 + ks] = *(const h8*)(wsf + WF_W1 +
            ((ks * 8 + half * 4 + n2) * 64 + lane) * 8);
#pragma unroll
    for (int n2 = 0; n2 < 4; ++n2) {
      f4 accA = {0.f, 0.f, 0.f, 0.f}, accB = {0.f, 0.f, 0.f, 0.f};
#pragma unroll
      for (int ks = 0; ks < 3; ++ks) {
        accA = __builtin_amdgcn_mfma_f32_16x16x32_f16(aohA[ks], bf[n2 * 3 + ks], accA, 0, 0, 0);
        accB = __builtin_amdgcn_mfma_f32_16x16x32_f16(aohB[ks], bf[n2 * 3 + ks], accB, 0, 0, 0);
      }
      const int col = (half * 4 + n2) * 16 + l15;
#pragma unroll
      for (int r = 0; r < 4; ++r) {
        const float vA = accA[r] > 0.f ? accA[r] : 0.f;
        const float vB = accB[r] > 0.f ? accB[r] : 0.f;
        pwA[(quad * 4 + r) * 136 + col] = f2h(vA);
        pwB[(quad * 4 + r) * 136 + col] = f2h(vB);
      }
    }
  }

  // S2: arch = LN1(h @ W2^T + b2); arch f16 -> pw*@0 stride 72,
  // residuals f32 in regs. bf shared across tiles.
  h8 a2A[4], a2B[4];
#pragma unroll
  for (int ks = 0; ks < 4; ++ks) {
    a2A[ks] = *(const h8*)(pwA + l15 * 136 + ks * 32 + quad * 8);
    a2B[ks] = *(const h8*)(pwB + l15 * 136 + ks * 32 + quad * 8);
  }
  float archresA[4][4], archresB[4][4];
  {
    float valA[4][4], valB[4][4];
#pragma unroll
    for (int half = 0; half < 2; ++half) {
      h8 bf[8];
#pragma unroll
      for (int n2 = 0; n2 < 2; ++n2)
#pragma unroll
        for (int ks = 0; ks < 4; ++ks)
          bf[n2 * 4 + ks] = *(const h8*)(wsf + WF_W2 +
              ((ks * 4 + half * 2 + n2) * 64 + lane) * 8);
#pragma unroll
      for (int n2 = 0; n2 < 2; ++n2) {
        f4 accA = {0.f, 0.f, 0.f, 0.f}, accB = {0.f, 0.f, 0.f, 0.f};
#pragma unroll
        for (int ks = 0; ks < 4; ++ks) {
          accA = __builtin_amdgcn_mfma_f32_16x16x32_f16(a2A[ks], bf[n2 * 4 + ks], accA, 0, 0, 0);
          accB = __builtin_amdgcn_mfma_f32_16x16x32_f16(a2B[ks], bf[n2 * 4 + ks], accB, 0, 0, 0);
        }
        const int nt = half * 2 + n2;
#pragma unroll
        for (int r = 0; r < 4; ++r) {
          valA[nt][r] = accA[r] + b2v[nt];
          valB[nt][r] = accB[r] + b2v[nt];
        }
      }
    }
#pragma unroll
    for (int r = 0; r < 4; ++r) {
      float sA = valA[0][r] + valA[1][r] + valA[2][r] + valA[3][r];
      float qA = valA[0][r] * valA[0][r] + valA[1][r] * valA[1][r] +
                 valA[2][r] * valA[2][r] + valA[3][r] * valA[3][r];
      float sB = valB[0][r] + valB[1][r] + valB[2][r] + valB[3][r];
      float qB = valB[0][r] * valB[0][r] + valB[1][r] * valB[1][r] +
                 valB[2][r] * valB[2][r] + valB[3][r] * valB[3][r];
#pragma unroll
      for (int off = 1; off <= 8; off <<= 1) {
        sA += __shfl_xor(sA, off);  qA += __shfl_xor(qA, off);
        sB += __shfl_xor(sB, off);  qB += __shfl_xor(qB, off);
      }
      const float meanA = sA * (1.f / 64.f);
      const float rstdA = rsqrtf(qA * (1.f / 64.f) - meanA * meanA + 1e-5f);
      const float meanB = sB * (1.f / 64.f);
      const float rstdB = rsqrtf(qB * (1.f / 64.f) - meanB * meanB + 1e-5f);
#pragma unroll
      for (int nt = 0; nt < 4; ++nt) {
        const int col = nt * 16 + l15;
        const float xnA = (valA[nt][r] - meanA) * rstdA * l1gv[nt] + l1bv[nt];
        const float xnB = (valB[nt][r] - meanB) * rstdB * l1gv[nt] + l1bv[nt];
        archresA[nt][r] = xnA;
        archresB[nt][r] = xnB;
        pwA[(quad * 4 + r) * 72 + col] = f2h(xnA);
        pwB[(quad * 4 + r) * 72 + col] = f2h(xnB);
      }
    }
  }

  // S3 producer: arch-token q1/k1/v1 -> LDS f16 (Q1@0, K1@1152, V1@2304)
  // per tile; bf shared.
  h8 at1A[2], at1B[2];
#pragma unroll
  for (int ks = 0; ks < 2; ++ks) {
    at1A[ks] = *(const h8*)(pwA + l15 * 72 + ks * 32 + quad * 8);
    at1B[ks] = *(const h8*)(pwB + l15 * 72 + ks * 32 + quad * 8);
  }
#pragma unroll
  for (int hh = 0; hh < 2; ++hh) {
    h8 bf[12];   // [h2][qkv][ks]
#pragma unroll
    for (int h2 = 0; h2 < 2; ++h2) {
      const int h = hh * 2 + h2;
#pragma unroll
      for (int ks = 0; ks < 2; ++ks) {
        bf[h2 * 6 + 0 + ks] = *(const h8*)(wsf + WF_IP + ((ks * 12 + h    ) * 64 + lane) * 8);
        bf[h2 * 6 + 2 + ks] = *(const h8*)(wsf + WF_IP + ((ks * 12 + h + 4) * 64 + lane) * 8);
        bf[h2 * 6 + 4 + ks] = *(const h8*)(wsf + WF_IP + ((ks * 12 + h + 8) * 64 + lane) * 8);
      }
    }
#pragma unroll
    for (int h2 = 0; h2 < 2; ++h2) {
      const int h = hh * 2 + h2;
      f4 aqA = {0.f,0.f,0.f,0.f}, akA = {0.f,0.f,0.f,0.f}, avA = {0.f,0.f,0.f,0.f};
      f4 aqB = {0.f,0.f,0.f,0.f}, akB = {0.f,0.f,0.f,0.f}, avB = {0.f,0.f,0.f,0.f};
#pragma unroll
      for (int ks = 0; ks < 2; ++ks) {
        aqA = __builtin_amdgcn_mfma_f32_16x16x32_f16(at1A[ks], bf[h2 * 6 + 0 + ks], aqA, 0, 0, 0);
        akA = __builtin_amdgcn_mfma_f32_16x16x32_f16(at1A[ks], bf[h2 * 6 + 2 + ks], akA, 0, 0, 0);
        avA = __builtin_amdgcn_mfma_f32_16x16x32_f16(at1A[ks], bf[h2 * 6 + 4 + ks], avA, 0, 0, 0);
        aqB = __builtin_amdgcn_mfma_f32_16x16x32_f16(at1B[ks], bf[h2 * 6 + 0 + ks], aqB, 0, 0, 0);
        akB = __builtin_amdgcn_mfma_f32_16x16x32_f16(at1B[ks], bf[h2 * 6 + 2 + ks], akB, 0, 0, 0);
        avB = __builtin_amdgcn_mfma_f32_16x16x32_f16(at1B[ks], bf[h2 * 6 + 4 + ks], avB, 0, 0, 0);
      }
      const int col = h * 16 + l15;
#pragma unroll
      for (int r = 0; r < 4; ++r) {
        const int row = quad * 4 + r;
        pwA[row * 72 + col]        = f2h(aqA[r]);
        pwA[1152 + row * 72 + col] = f2h(akA[r]);
        pwA[2304 + row * 72 + col] = f2h(avA[r]);
        pwB[row * 72 + col]        = f2h(aqB[r]);
        pwB[1152 + row * 72 + col] = f2h(akB[r]);
        pwB[2304 + row * 72 + col] = f2h(avB[r]);
      }
    }
  }

  // S4 consumer per tile: lane = (sample=l15, head=quad); fdot2 scores.
#pragma unroll
  for (int tile = 0; tile < 2; ++tile) {
    unsigned short* pw = tile ? pwB : pwA;
    const int hwrow = tile ? hwrowB : hwrowA;
    const int qb = quad * 16;
    const unsigned short* q1p = pw + l15 * 72 + qb;
    const h8 q1a = *(const h8*)(q1p),          q1b = *(const h8*)(q1p + 8);
    const h8 k1a = *(const h8*)(q1p + 1152),   k1b = *(const h8*)(q1p + 1160);
    const h8 v1a = *(const h8*)(q1p + 2304),   v1b = *(const h8*)(q1p + 2312);
    const int tb = hwrow * 64 + qb;
    const h8 Q0a = *(const h8*)(wsf + TQ0 + tb),  Q0b = *(const h8*)(wsf + TQ0 + tb + 8);
    const h8 K0a = *(const h8*)(wsf + TK0 + tb),  K0b = *(const h8*)(wsf + TK0 + tb + 8);
    const h8 VBa = *(const h8*)(wsf + TV0B + tb), VBb = *(const h8*)(wsf + TV0B + tb + 8);
    const h8 VRa = *(const h8*)(wsf + TV0R + tb), VRb = *(const h8*)(wsf + TV0R + tb + 8);
    const h8 bqa = *(const h8*)(wsf + TBQ + qb),  bqb = *(const h8*)(wsf + TBQ + qb + 8);
    const h8 dka = k1a - K0a, dkb = k1b - K0b;   // bk cancels
    const float d0 = dot8(Q0a, dka, dot8(Q0b, dkb, 0.f));
    const float d1 = dot8(q1a, dka, dot8(q1b, dkb,
                     dot8(bqa, dka, dot8(bqb, dkb, 0.f))));
    const float a01 = 1.f / (1.f + __expf(-d0 * 0.25f));
    const float a11 = 1.f / (1.f + __expf(-d1 * 0.25f));
    const h8 dva = v1a - VRa, dvb = v1b - VRb;   // bv cancels in dv
    h8 c0a, c0b, c1a, c1b;                       // ctx math in f32
#pragma unroll
    for (int j = 0; j < 8; ++j) {
      const float vb0 = (float)VBa[j], dv0 = (float)dva[j];
      const float vb1 = (float)VBb[j], dv1 = (float)dvb[j];
      c0a[j] = (_Float16)(vb0 + a01 * dv0);
      c0b[j] = (_Float16)(vb1 + a01 * dv1);
      c1a[j] = (_Float16)(vb0 + a11 * dv0);
      c1b[j] = (_Float16)(vb1 + a11 * dv1);
    }
    *(h8*)(pw + l15 * 72 + qb)            = c0a;
    *(h8*)(pw + l15 * 72 + qb + 8)        = c0b;
    *(h8*)(pw + (16 + l15) * 72 + qb)     = c1a;
    *(h8*)(pw + (16 + l15) * 72 + qb + 8) = c1b;
  }

  // S5: out_proj + residual + LN2 + mean-pool -> pool f16 @0, per tile.
  // bf[8] loaded once; tile A finished fully before tile B (caps regs).
  {
    h8 bf[8];
#pragma unroll
    for (int nt = 0; nt < 4; ++nt)
#pragma unroll
      for (int ks = 0; ks < 2; ++ks)
        bf[nt * 2 + ks] = *(const h8*)(wsf + WF_OP + ((ks * 4 + nt) * 64 + lane) * 8);
#pragma unroll
    for (int tile = 0; tile < 2; ++tile) {
      unsigned short* pw = tile ? pwB : pwA;
      h8 ca[2][2];
#pragma unroll
      for (int mt = 0; mt < 2; ++mt)
#pragma unroll
        for (int ks = 0; ks < 2; ++ks)
          ca[mt][ks] = *(const h8*)(pw + (mt * 16 + l15) * 72 + ks * 32 + quad * 8);
      f4 oacc[2][4];
#pragma unroll
      for (int nt = 0; nt < 4; ++nt)
#pragma unroll
        for (int mt = 0; mt < 2; ++mt) {
          f4 acc = {0.f, 0.f, 0.f, 0.f};
          acc = __builtin_amdgcn_mfma_f32_16x16x32_f16(ca[mt][0], bf[nt * 2 + 0], acc, 0, 0, 0);
          acc = __builtin_amdgcn_mfma_f32_16x16x32_f16(ca[mt][1], bf[nt * 2 + 1], acc, 0, 0, 0);
          oacc[mt][nt] = acc;
        }
      float pool[4][4];
#pragma unroll
      for (int mt = 0; mt < 2; ++mt) {
        float val[4][4];
#pragma unroll
        for (int r = 0; r < 4; ++r) {
          if (mt == 0) {
            const int hr = __shfl(hwv, tile * 16 + quad * 4 + r);
#pragma unroll
            for (int nt = 0; nt < 4; ++nt)
              val[nt][r] = oacc[0][nt][r] + opbv[nt] + g_hwe[hr * 64 + nt * 16 + l15];
          } else {
#pragma unroll
            for (int nt = 0; nt < 4; ++nt)
              val[nt][r] = oacc[1][nt][r] + opbv[nt] +
                           (tile ? archresB[nt][r] : archresA[nt][r]);
          }
        }
#pragma unroll
        for (int r = 0; r < 4; ++r) {
          float s = val[0][r] + val[1][r] + val[2][r] + val[3][r];
          float q = val[0][r] * val[0][r] + val[1][r] * val[1][r] +
                    val[2][r] * val[2][r] + val[3][r] * val[3][r];
#pragma unroll
          for (int off = 1; off <= 8; off <<= 1) {
            s += __shfl_xor(s, off);
            q += __shfl_xor(q, off);
          }
          const float mean = s * (1.f / 64.f);
          const float var  = q * (1.f / 64.f) - mean * mean;
          const float rstd = rsqrtf(var + 1e-5f);
#pragma unroll
          for (int nt = 0; nt < 4; ++nt) {
            const float xn = (val[nt][r] - mean) * rstd * l2gv[nt] + l2bv[nt];
            if (mt == 0) pool[nt][r] = 0.5f * xn;
            else         pool[nt][r] += 0.5f * xn;
          }
        }
      }
#pragma unroll
      for (int nt = 0; nt < 4; ++nt)
#pragma unroll
        for (int r = 0; r < 4; ++r)
          pw[(quad * 4 + r) * 72 + nt * 16 + l15] = f2h(pool[nt][r]);
    }
  }

  // S6: head, per tile; bf[4] loaded once.
  {
    h8 bf[4];
#pragma unroll
    for (int nt = 0; nt < 2; ++nt)
#pragma unroll
      for (int ks = 0; ks < 2; ++ks)
        bf[nt * 2 + ks] = *(const h8*)(wsf + WF_W3 + ((ks * 2 + nt) * 64 + lane) * 8);
#pragma unroll
    for (int tile = 0; tile < 2; ++tile) {
      unsigned short* pw = tile ? pwB : pwA;
      h8 pa[2];
#pragma unroll
      for (int ks = 0; ks < 2; ++ks)
        pa[ks] = *(const h8*)(pw + l15 * 72 + ks * 32 + quad * 8);
      float part[4] = {0.f, 0.f, 0.f, 0.f};
#pragma unroll
      for (int nt = 0; nt < 2; ++nt) {
        f4 acc = {0.f, 0.f, 0.f, 0.f};
        acc = __builtin_amdgcn_mfma_f32_16x16x32_f16(pa[0], bf[nt * 2 + 0], acc, 0, 0, 0);
        acc = __builtin_amdgcn_mfma_f32_16x16x32_f16(pa[1], bf[nt * 2 + 1], acc, 0, 0, 0);
#pragma unroll
        for (int r = 0; r < 4; ++r) {
          float y = acc[r] + b3v[nt];
          y = y > 0.f ? y : 0.f;
          part[r] += y * w4vv[nt];
        }
      }
#pragma unroll
      for (int off = 1; off <= 8; off <<= 1)
#pragma unroll
        for (int r = 0; r < 4; ++r)
          part[r] += __shfl_xor(part[r], off);
      if (l15 == 0) {
#pragma unroll
        for (int r = 0; r < 4; ++r)
          g_out[m0 + tile * 16 + quad * 4 + r] = part[r] + b4v;
      }
    }
  }
}

extern "C" void kernel_launch(void* const* d_in, const int* in_sizes, int n_in,
                              void* d_out, int out_size, void* d_ws, size_t ws_size,
                              hipStream_t stream) {
  (void)in_sizes; (void)n_in; (void)out_size; (void)ws_size;
  unsigned short* ws = (unsigned short*)d_ws;

  k_pre<<<64, 256, 0, stream>>>(
      (const float*)d_in[3], (const float*)d_in[4], (const float*)d_in[5],
      (const float*)d_in[6], (const float*)d_in[10], (const float*)d_in[11],
      (const float*)d_in[12], (const float*)d_in[16], ws);

  k_fused<<<4096, 128, 0, stream>>>(
      (const int*)d_in[0],
      (const int*)d_in[1], (const int*)d_in[2],
      (const float*)d_in[3],
      (const float*)d_in[7],
      (const float*)d_in[8], (const float*)d_in[9],
      (const float*)d_in[13],
      (const float*)d_in[14], (const float*)d_in[15],
      (const float*)d_in[17], (const float*)d_in[18],
      (const float*)d_in[19],
      ws, (float*)d_out);
}